// Round 5
// baseline (1146.761 us; speedup 1.0000x reference)
//
#include <hip/hip_runtime.h>
#include <stdint.h>

#define NB   8
#define NPTS 4096
#define CINV 64
#define MC   1024
#define KNB  64
#define NE   (NB*MC*KNB)
#define K1   67
#define CH1  64
#define CH2  64
#define CH3  128
#define NSLOT 64
#define CAP  2048
#define NTASK (NB*MC)
#define NBLK 256      // == #CUs

typedef unsigned short u16;
typedef unsigned int   u32;
typedef unsigned long long u64;

static __device__ __forceinline__ float bf2f(u16 b){ return __uint_as_float(((u32)b)<<16); }
static __device__ __forceinline__ u16  f2bf(float f){
  u32 u = __float_as_uint(f);
  return (u16)((u + 0x7fffu + ((u>>16)&1u)) >> 16);
}
// Exact replica of reference distance: square each diff, sum as (x+y)+z, NO fma contraction.
static __device__ __forceinline__ float d2ref(float ax,float ay,float az,
                                              float bx,float by,float bz){
  float dx = ax-bx, dy = ay-by, dz = az-bz;
  return __fadd_rn(__fadd_rn(__fmul_rn(dx,dx), __fmul_rn(dy,dy)), __fmul_rn(dz,dz));
}
static __device__ __forceinline__ float wsum(float v){
  #pragma unroll
  for (int off = 32; off > 0; off >>= 1) v += __shfl_xor(v, off);
  return v;
}
// ---- packed-FP32 VOP3P helpers: one instr = two f32 lanes (CDNA "DPFP32").
// Result halves are separate regs of the pair, so no unpack cost.
// pk_sub: a + (-b) which is bit-identical to a - b (IEEE).
static __device__ __forceinline__ double pk_sub(double a, double b){
  double r;
  asm("v_pk_add_f32 %0, %1, %2 neg_lo:[0,1] neg_hi:[0,1]" : "=v"(r) : "v"(a), "v"(b));
  return r;
}
static __device__ __forceinline__ double pk_add(double a, double b){
  double r;
  asm("v_pk_add_f32 %0, %1, %2" : "=v"(r) : "v"(a), "v"(b));
  return r;
}
static __device__ __forceinline__ double pk_mul(double a, double b){
  double r;
  asm("v_pk_mul_f32 %0, %1, %2" : "=v"(r) : "v"(a), "v"(b));
  return r;
}
static __device__ __forceinline__ double packf2(float lo, float hi){
  return __hiloint2double(__float_as_int(hi), __float_as_int(lo));
}
static __device__ __forceinline__ float pklo(double d){ return __int_as_float(__double2loint(d)); }
static __device__ __forceinline__ float pkhi(double d){ return __int_as_float(__double2hiint(d)); }

// ---- DPP primitives (pure VALU, no DS pipe) ----
template<int CTRL, int RMASK>
static __device__ __forceinline__ float dppmaxstep(float v){
  int t = __builtin_amdgcn_update_dpp(__float_as_int(v), __float_as_int(v),
                                      CTRL, RMASK, 0xF, false);
  return fmaxf(v, __int_as_float(t));
}
template<int CTRL, int RMASK>
static __device__ __forceinline__ float dppminstep(float v){
  int t = __builtin_amdgcn_update_dpp(__float_as_int(v), __float_as_int(v),
                                      CTRL, RMASK, 0xF, false);
  return fminf(v, __int_as_float(t));
}
template<int CTRL, int RMASK>
static __device__ __forceinline__ float dppaddstep(float v){
  // old = 0 so row-masked lanes add 0 (exact-once summation)
  int t = __builtin_amdgcn_update_dpp(0, __float_as_int(v), CTRL, RMASK, 0xF, false);
  return v + __int_as_float(t);
}
// Full-wave reductions; result valid in LANE 63 only.
static __device__ __forceinline__ float dppsum63(float v){
  v = dppaddstep<0xB1,0xF>(v); v = dppaddstep<0x4E,0xF>(v); v = dppaddstep<0x141,0xF>(v);
  v = dppaddstep<0x140,0xF>(v); v = dppaddstep<0x142,0xA>(v); v = dppaddstep<0x143,0xC>(v);
  return v;
}
static __device__ __forceinline__ float dppmax63(float v){
  v = dppmaxstep<0xB1,0xF>(v); v = dppmaxstep<0x4E,0xF>(v); v = dppmaxstep<0x141,0xF>(v);
  v = dppmaxstep<0x140,0xF>(v); v = dppmaxstep<0x142,0xA>(v); v = dppmaxstep<0x143,0xC>(v);
  return v;
}
static __device__ __forceinline__ float dppmin63(float v){
  v = dppminstep<0xB1,0xF>(v); v = dppminstep<0x4E,0xF>(v); v = dppminstep<0x141,0xF>(v);
  v = dppminstep<0x140,0xF>(v); v = dppminstep<0x142,0xA>(v); v = dppminstep<0x143,0xC>(v);
  return v;
}
// ---- f64-keyed argmax: key = bits[dist(f32) : ~idx]. Both positive doubles,
// so IEEE f64 ordering == u64 bit ordering: v_max_f64 == (max dist, lowest idx on tie).
static __device__ __forceinline__ double kpack(float d, int ni){
  return __hiloint2double(__float_as_int(d), ni);
}
template<int CTRL, int RMASK>
static __device__ __forceinline__ double dppk64(double k){
  int hi = __double2hiint(k), lo = __double2loint(k);
  int thi = __builtin_amdgcn_update_dpp(hi, hi, CTRL, RMASK, 0xF, false);
  int tlo = __builtin_amdgcn_update_dpp(lo, lo, CTRL, RMASK, 0xF, false);
  return fmax(k, __hiloint2double(thi, tlo));
}

// ---------------------------------------------------------------- fused front kernel
struct FpsL {
  float4 pq[NPTS];   // (x,y,z,0) per point: q-fetch = one ds_read_b128
  int   sIdx[MC];
  double candD[16];  // keyed candidates, double-buffered 2x8
  float4 cbuf[16];   // centroid staging: flush 16 rows per tile to global
};
struct WkL {
  u64   keys[CAP];        // ball-query sort keys
  float Hs[64*69];        // stage-1 H tile (odd pitch)
  int   nbrS[64];
  float red[8][16];
  float cxyz[3];
  int   scnt;
  int   task;
};
union FrontL { FpsL f; WkL w; };

__global__ __launch_bounds__(512) void k_front(const float* __restrict__ x,
                                               const float* __restrict__ pos,
                                               float* __restrict__ centf,
                                               float* __restrict__ out_cent,
                                               float* __restrict__ out_bsel,
                                               const float* __restrict__ W1,
                                               float* __restrict__ Spart,
                                               u16* __restrict__ y1g,
                                               int* __restrict__ cntpc,
                                               int* __restrict__ cnt_total,
                                               int* __restrict__ progress,
                                               int* __restrict__ taskctr) {
  __shared__ FrontL L;
  const int tid = threadIdx.x;

  if (blockIdx.x < NB) {
    // ============ FPS producer: 8 waves x 8 pts/lane, packed-f32 scan,
    // f64-keyed argmax, 1 barrier/iter, no ballots, no bpermute.
    const int b = blockIdx.x;
    for (int i = tid; i < NPTS; i += 512) {
      size_t o = ((size_t)b*NPTS + i)*3;
      L.f.pq[i] = make_float4(pos[o], pos[o+1], pos[o+2], 0.f);
    }
    __syncthreads();

    // per-lane 8 points as 4 packed pairs per coordinate
    double cx2[4], cy2[4], cz2[4];
    float dist[8];
    int nio[8];
    #pragma unroll
    for (int j = 0; j < 4; ++j) {
      int p = tid*8 + 2*j;
      float4 p0 = L.f.pq[p], p1 = L.f.pq[p+1];
      cx2[j] = packf2(p0.x, p1.x);
      cy2[j] = packf2(p0.y, p1.y);
      cz2[j] = packf2(p0.z, p1.z);
    }
    #pragma unroll
    for (int j = 0; j < 8; ++j) { dist[j] = 1e10f; nio[j] = ~(tid*8 + j); }
    const int lane = tid & 63, w = tid >> 6;
    float4 q0 = L.f.pq[0];
    float qx = q0.x, qy = q0.y, qz = q0.z;
    if (tid == 0) {
      L.f.sIdx[0] = 0;
      L.f.cbuf[0] = make_float4(qx, qy, qz, 0.f);
    }

    for (int it = 1; it < MC; ++it) {
      // ---- packed scan: 2 points per instr; rounding identical to d2ref
      double qx2 = packf2(qx, qx), qy2 = packf2(qy, qy), qz2 = packf2(qz, qz);
      #pragma unroll
      for (int j = 0; j < 4; ++j) {
        double dx = pk_sub(cx2[j], qx2);
        double dy = pk_sub(cy2[j], qy2);
        double dz = pk_sub(cz2[j], qz2);
        double xx = pk_mul(dx, dx);
        double yy = pk_mul(dy, dy);
        double ss = pk_add(xx, yy);
        double zz = pk_mul(dz, dz);
        double dd = pk_add(ss, zz);
        dist[2*j]   = fminf(dist[2*j],   pklo(dd));
        dist[2*j+1] = fminf(dist[2*j+1], pkhi(dd));
      }
      // ---- keyed pairwise tree over 8 points (7 x v_max_f64)
      double t0 = fmax(kpack(dist[0], nio[0]), kpack(dist[1], nio[1]));
      double t1 = fmax(kpack(dist[2], nio[2]), kpack(dist[3], nio[3]));
      double t2 = fmax(kpack(dist[4], nio[4]), kpack(dist[5], nio[5]));
      double t3 = fmax(kpack(dist[6], nio[6]), kpack(dist[7], nio[7]));
      double bk = fmax(fmax(t0, t1), fmax(t2, t3));
      // ---- wave keyed reduce (6 DPP steps), winner key valid in lane 63
      bk = dppk64<0xB1,0xF>(bk);
      bk = dppk64<0x4E,0xF>(bk);
      bk = dppk64<0x141,0xF>(bk);
      bk = dppk64<0x140,0xF>(bk);
      bk = dppk64<0x142,0xA>(bk);
      bk = dppk64<0x143,0xC>(bk);
      if (lane == 63) L.f.candD[(it & 1)*8 + w] = bk;
      __syncthreads();
      // ---- resolve 8 candidates branch-free (3 keyed DPP steps, all lanes uniform)
      double ck = L.f.candD[(it & 1)*8 + (lane & 7)];
      ck = dppk64<0xB1,0xF>(ck);
      ck = dppk64<0x4E,0xF>(ck);
      ck = dppk64<0x141,0xF>(ck);
      int wi = (int)(~(u32)__double2loint(ck));   // winning point index (uniform)
      float4 qv = L.f.pq[wi];                     // one ds_read_b128 broadcast
      qx = qv.x; qy = qv.y; qz = qv.z;
      // flush PREVIOUS 16-row tile then release-publish progress
      if ((it & 15) == 0 && tid < 16) {
        int mrow = it - 16 + tid;
        float4 cc = L.f.cbuf[tid];
        int r = b*MC + mrow;
        centf[r*3+0] = cc.x; centf[r*3+1] = cc.y; centf[r*3+2] = cc.z;
        if (tid == 0)
          __hip_atomic_store(progress + b, it, __ATOMIC_RELEASE, __HIP_MEMORY_SCOPE_AGENT);
      }
      if (tid == 0) {
        L.f.sIdx[it] = wi;
        L.f.cbuf[it & 15] = make_float4(qx, qy, qz, 0.f);
      }
    }
    __syncthreads();
    // final tile flush (rows MC-16..MC-1) + progress = MC
    if (tid < 16) {
      int mrow = MC - 16 + tid;
      float4 cc = L.f.cbuf[tid];
      int r = b*MC + mrow;
      centf[r*3+0] = cc.x; centf[r*3+1] = cc.y; centf[r*3+2] = cc.z;
      if (tid == 0)
        __hip_atomic_store(progress + b, MC, __ATOMIC_RELEASE, __HIP_MEMORY_SCOPE_AGENT);
    }
    // epilogue: out_cent / out_bsel from sIdx (off the critical path)
    for (int m2_ = tid; m2_ < MC; m2_ += 512) {
      int i = L.f.sIdx[m2_];
      int r = b*MC + m2_;
      float4 pv = L.f.pq[i];
      out_cent[r*3+0] = pv.x; out_cent[r*3+1] = pv.y; out_cent[r*3+2] = pv.z;
      out_bsel[r] = (float)b;
    }
    return;
  }

  // ============ persistent workers: ball query + stage-1 per centroid (512 thr)
  for (;;) {
    if (tid == 0) {
      int t = atomicAdd(taskctr, 1);
      L.w.task = t;
      if (t < NTASK) {
        int m = t >> 3, b = t & 7;
        while (__hip_atomic_load(progress + b, __ATOMIC_ACQUIRE, __HIP_MEMORY_SCOPE_AGENT) < m + 1)
          __builtin_amdgcn_s_sleep(8);
        int bm = b*MC + m;
        L.w.cxyz[0] = __hip_atomic_load(centf + bm*3 + 0, __ATOMIC_RELAXED, __HIP_MEMORY_SCOPE_AGENT);
        L.w.cxyz[1] = __hip_atomic_load(centf + bm*3 + 1, __ATOMIC_RELAXED, __HIP_MEMORY_SCOPE_AGENT);
        L.w.cxyz[2] = __hip_atomic_load(centf + bm*3 + 2, __ATOMIC_RELAXED, __HIP_MEMORY_SCOPE_AGENT);
      }
      L.w.scnt = 0;
    }
    __syncthreads();
    const int t = L.w.task;
    if (t >= NTASK) return;
    const int m = t >> 3, b = t & 7, bm = b*MC + m;
    const float cx = L.w.cxyz[0], cy = L.w.cxyz[1], cz = L.w.cxyz[2];

    // ---- ball query (exact ref semantics)
    for (int i = tid; i < NPTS; i += 512) {
      size_t o = ((size_t)b*NPTS + i)*3;
      float d = d2ref(cx, cy, cz, pos[o], pos[o+1], pos[o+2]);
      if (d <= 0.04f) {
        int p = atomicAdd(&L.w.scnt, 1);
        if (p < CAP) L.w.keys[p] = ((u64)__float_as_uint(d) << 32) | (u32)i;
      }
    }
    __syncthreads();
    int n = L.w.scnt; if (n > CAP) n = CAP;
    int P = 64; while (P < n) P <<= 1;
    for (int i = n + tid; i < P; i += 512) L.w.keys[i] = ~0ull;
    __syncthreads();
    for (int ks = 2; ks <= P; ks <<= 1)
      for (int js = ks >> 1; js > 0; js >>= 1) {
        for (int i = tid; i < P; i += 512) {
          int l = i ^ js;
          if (l > i) {
            u64 a = L.w.keys[i], c = L.w.keys[l];
            bool up = ((i & ks) == 0);
            if ((a > c) == up) { L.w.keys[i] = c; L.w.keys[l] = a; }
          }
        }
        __syncthreads();
      }
    const int c = n < KNB ? n : KNB;
    if (tid < KNB) L.w.nbrS[tid] = (tid < c) ? (int)(u32)(L.w.keys[tid] & 0xffffffffu) : 0;
    if (tid == 0) { cntpc[bm] = c; atomicAdd(cnt_total, c); }
    __syncthreads();

    // ---- stage-1: H = [x_j, p_j - c_i] (64x67) staged in LDS
    {
      const int ge = tid >> 3, qb = tid & 7;
      const float4* xr = (const float4*)(x + ((size_t)(b*NPTS + L.w.nbrS[ge]))*CINV);
      #pragma unroll
      for (int rep = 0; rep < 2; ++rep) {
        int q = qb + rep*8;
        float4 v = xr[q];
        float* d = L.w.Hs + ge*69 + q*4;
        d[0] = v.x; d[1] = v.y; d[2] = v.z; d[3] = v.w;
      }
    }
    if (tid < 64) {
      int row = b*NPTS + L.w.nbrS[tid];
      L.w.Hs[tid*69+64] = pos[(size_t)row*3+0] - cx;
      L.w.Hs[tid*69+65] = pos[(size_t)row*3+1] - cy;
      L.w.Hs[tid*69+66] = pos[(size_t)row*3+2] - cz;
    }
    __syncthreads();

    // ---- GEMM: thread = (edge, col of 8 ch); W via wave-uniform SCALAR loads
    const int edge = tid & 63;
    const int col  = __builtin_amdgcn_readfirstlane(tid >> 6);  // 0..7
    float acc[8];
    #pragma unroll
    for (int j = 0; j < 8; ++j) acc[j] = 0.f;
    const float* hrow = L.w.Hs + edge*69;
    const float* wcol = W1 + col*8;
    for (int k = 0; k < K1; ++k) {
      float hk = hrow[k];
      const float4* w4 = (const float4*)(wcol + k*CH1);
      float4 a = w4[0], bq = w4[1];
      acc[0] = fmaf(hk, a.x,  acc[0]); acc[1] = fmaf(hk, a.y,  acc[1]);
      acc[2] = fmaf(hk, a.z,  acc[2]); acc[3] = fmaf(hk, a.w,  acc[3]);
      acc[4] = fmaf(hk, bq.x, acc[4]); acc[5] = fmaf(hk, bq.y, acc[5]);
      acc[6] = fmaf(hk, bq.z, acc[6]); acc[7] = fmaf(hk, bq.w, acc[7]);
    }
    const bool valid = edge < c;
    #pragma unroll
    for (int j = 0; j < 8; ++j) acc[j] = valid ? acc[j] : 0.f;
    u32* dst = (u32*)(y1g + ((size_t)bm*64 + edge)*CH1 + col*8);
    #pragma unroll
    for (int j = 0; j < 4; ++j)
      dst[j] = (u32)f2bf(acc[2*j]) | ((u32)f2bf(acc[2*j+1]) << 16);
    #pragma unroll
    for (int j = 0; j < 8; ++j) {
      float s = wsum(acc[j]);
      float q = wsum(acc[j]*acc[j]);
      if (edge == 0) { L.w.red[col][j] = s; L.w.red[col][8+j] = q; }
    }
    __syncthreads();
    const int slot = bm & (NSLOT-1);
    if (tid < 64)  atomicAdd(&Spart[slot*256 + tid], L.w.red[tid>>3][tid&7]);
    else if (tid < 128) {
      int cc = tid - 64;
      atomicAdd(&Spart[slot*256 + 128 + cc], L.w.red[cc>>3][8 + (cc&7)]);
    }
    // top-of-loop __syncthreads() isolates this task's LDS reads from next task's writes
  }
}

// ---------------------------------------------------------------- stage 2: relu(bn1(y1)) @ W2
__global__ __launch_bounds__(256) void k_s2(const u16* __restrict__ y1g,
                                            const float* __restrict__ SC,
                                            const float* __restrict__ W2,
                                            const int* __restrict__ cntpc,
                                            float* __restrict__ Spart,
                                            u16* __restrict__ y2g) {
  __shared__ float Hs[64*65];
  __shared__ float ABs[128];
  __shared__ float red[4][32];
  __shared__ int   cntS;
  const int tid = threadIdx.x, bm = blockIdx.x;
  if (tid == 0) cntS = cntpc[bm];
  if (tid < 128) ABs[tid] = SC[tid];            // A1(64) B1(64)
  __syncthreads();
  {
    const u32* yt = (const u32*)y1g + (size_t)bm*2048;  // 64 edges * 32 u32
    #pragma unroll
    for (int rep = 0; rep < 8; ++rep) {
      int g = rep*256 + tid;
      int e = g >> 5, c2 = g & 31, ch = c2*2;
      u32 v = yt[g];
      float lo = fmaxf(fmaf(bf2f((u16)(v & 0xffff)), ABs[ch],   ABs[64+ch]),   0.f);
      float hi = fmaxf(fmaf(bf2f((u16)(v >> 16)),    ABs[ch+1], ABs[64+ch+1]), 0.f);
      Hs[e*65 + ch] = lo; Hs[e*65 + ch + 1] = hi;
    }
  }
  __syncthreads();

  const int edge = tid & 63;
  const int col  = __builtin_amdgcn_readfirstlane(tid >> 6);
  float acc[16];
  #pragma unroll
  for (int j = 0; j < 16; ++j) acc[j] = 0.f;
  const float* hrow = Hs + edge*65;
  const float* wcol = W2 + col*16;
  for (int k = 0; k < CH1; ++k) {
    float hk = hrow[k];
    const float4* w4 = (const float4*)(wcol + k*CH2);
    #pragma unroll
    for (int q = 0; q < 4; ++q) {
      float4 wv = w4[q];
      acc[q*4+0] = fmaf(hk, wv.x, acc[q*4+0]);
      acc[q*4+1] = fmaf(hk, wv.y, acc[q*4+1]);
      acc[q*4+2] = fmaf(hk, wv.z, acc[q*4+2]);
      acc[q*4+3] = fmaf(hk, wv.w, acc[q*4+3]);
    }
  }
  const bool valid = edge < cntS;
  #pragma unroll
  for (int j = 0; j < 16; ++j) acc[j] = valid ? acc[j] : 0.f;
  u32* dst = (u32*)(y2g + ((size_t)bm*64 + edge)*CH2 + col*16);
  #pragma unroll
  for (int j = 0; j < 8; ++j)
    dst[j] = (u32)f2bf(acc[2*j]) | ((u32)f2bf(acc[2*j+1]) << 16);
  #pragma unroll
  for (int j = 0; j < 16; ++j) {
    float s = dppsum63(acc[j]);
    float q = dppsum63(acc[j]*acc[j]);
    if (edge == 63) { red[col][j] = s; red[col][16+j] = q; }
  }
  __syncthreads();
  const int slot = bm & (NSLOT-1);
  if (tid < 64)  atomicAdd(&Spart[slot*256 + tid], red[tid>>4][tid&15]);
  else if (tid < 128) {
    int c = tid - 64;
    atomicAdd(&Spart[slot*256 + 128 + c], red[c>>4][16 + (c&15)]);
  }
}

// ---------------------------------------------------------------- stage 3: relu(bn2(y2)) @ W3, + per-(bm,ch) max/min of f32 y3
__global__ __launch_bounds__(256) void k_s3(const u16* __restrict__ y2g,
                                            const float* __restrict__ SC,
                                            const float* __restrict__ W3,
                                            const int* __restrict__ cntpc,
                                            float* __restrict__ Spart,
                                            float* __restrict__ mxmn) {
  __shared__ float Hs[64*65];
  __shared__ float ABs[128];
  __shared__ float red[4][64];
  __shared__ float redm[4][64];
  __shared__ int   cntS;
  const int tid = threadIdx.x, bm = blockIdx.x;
  if (tid == 0) cntS = cntpc[bm];
  if (tid < 128) ABs[tid] = SC[128 + tid];      // A2(64) B2(64)
  __syncthreads();
  {
    const u32* yt = (const u32*)y2g + (size_t)bm*2048;
    #pragma unroll
    for (int rep = 0; rep < 8; ++rep) {
      int g = rep*256 + tid;
      int e = g >> 5, c2 = g & 31, ch = c2*2;
      u32 v = yt[g];
      float lo = fmaxf(fmaf(bf2f((u16)(v & 0xffff)), ABs[ch],   ABs[64+ch]),   0.f);
      float hi = fmaxf(fmaf(bf2f((u16)(v >> 16)),    ABs[ch+1], ABs[64+ch+1]), 0.f);
      Hs[e*65 + ch] = lo; Hs[e*65 + ch + 1] = hi;
    }
  }
  __syncthreads();

  const int edge = tid & 63;
  const int col  = __builtin_amdgcn_readfirstlane(tid >> 6);  // owns 32 of 128 ch
  float acc[32];
  #pragma unroll
  for (int j = 0; j < 32; ++j) acc[j] = 0.f;
  const float* hrow = Hs + edge*65;
  const float* wcol = W3 + col*32;
  for (int k = 0; k < CH2; ++k) {
    float hk = hrow[k];
    const float4* w4 = (const float4*)(wcol + k*CH3);
    #pragma unroll
    for (int q = 0; q < 8; ++q) {
      float4 wv = w4[q];
      acc[q*4+0] = fmaf(hk, wv.x, acc[q*4+0]);
      acc[q*4+1] = fmaf(hk, wv.y, acc[q*4+1]);
      acc[q*4+2] = fmaf(hk, wv.z, acc[q*4+2]);
      acc[q*4+3] = fmaf(hk, wv.w, acc[q*4+3]);
    }
  }
  const bool valid = edge < cntS;
  #pragma unroll
  for (int j = 0; j < 32; ++j) {
    float mxv = valid ? acc[j] : -1e30f;
    float mnv = valid ? acc[j] :  1e30f;
    float av  = valid ? acc[j] : 0.f;
    float s  = dppsum63(av);
    float q  = dppsum63(av*av);
    float mx = dppmax63(mxv);
    float mn = dppmin63(mnv);
    if (edge == 63) { red[col][j] = s; red[col][32+j] = q;
                      redm[col][j] = mx; redm[col][32+j] = mn; }
  }
  __syncthreads();
  const int slot = bm & (NSLOT-1);
  if (tid < 128) {
    atomicAdd(&Spart[slot*256 + tid], red[tid>>5][tid&31]);
    mxmn[(size_t)bm*256 + tid] = redm[tid>>5][tid&31];            // max(y3) per ch
  } else {
    int c = tid - 128;
    atomicAdd(&Spart[slot*256 + 128 + c], red[c>>5][32 + (c&31)]);
    mxmn[(size_t)bm*256 + 128 + c] = redm[c>>5][32 + (c&31)];     // min(y3) per ch
  }
}

// ---------------------------------------------------------------- stage 4: bn3+relu+maxpool from per-block max/min
// max_e relu(a*y+b) = relu(a*max_e(y)+b) for a>0 (monotone correctly-rounded ops
// commute with max); use min_e(y) for a<0. Exact vs the elementwise scan.
__global__ __launch_bounds__(128) void k_s4(const float* __restrict__ mxmn,
                                            const float* __restrict__ SC,
                                            float* __restrict__ out0) {
  const int tid = threadIdx.x, bm = blockIdx.x;
  const float a = SC[256 + tid], b = SC[384 + tid];
  const float mx = mxmn[(size_t)bm*256 + tid];
  const float mn = mxmn[(size_t)bm*256 + 128 + tid];
  const float v = (a > 0.f) ? mx : mn;
  out0[(size_t)bm*CH3 + tid] = fmaxf(fmaf(v, a, b), 0.f);
}

// ---------------------------------------------------------------- finalize
__global__ void k_finalize(const float* __restrict__ Spart,
                           const float* __restrict__ g, const float* __restrict__ bb,
                           const int* __restrict__ cnt_total,
                           float* __restrict__ Aout, float* __restrict__ Bout, int C) {
  int c = threadIdx.x;
  if (c < C) {
    float s = 0.f, q = 0.f;
    for (int sl = 0; sl < NSLOT; ++sl) {
      s += Spart[sl*256 + c];
      q += Spart[sl*256 + 128 + c];
    }
    float n = (float)(*cnt_total); if (n < 1.f) n = 1.f;
    float mu  = s / n;
    float var = q / n - mu*mu; if (var < 0.f) var = 0.f;
    float inv = 1.0f / sqrtf(var + 1e-5f);
    float a = g[c] * inv;
    Aout[c] = a;
    Bout[c] = bb[c] - mu*a;
  }
}

// ---------------------------------------------------------------- host
extern "C" void kernel_launch(void* const* d_in, const int* in_sizes, int n_in,
                              void* d_out, int out_size, void* d_ws, size_t ws_size,
                              hipStream_t stream) {
  (void)in_sizes; (void)n_in; (void)out_size; (void)ws_size;
  const float* x   = (const float*)d_in[0];
  const float* pos = (const float*)d_in[1];
  const float* W1  = (const float*)d_in[3];
  const float* g1  = (const float*)d_in[4];
  const float* b1  = (const float*)d_in[5];
  const float* W2  = (const float*)d_in[6];
  const float* g2  = (const float*)d_in[7];
  const float* b2  = (const float*)d_in[8];
  const float* W3  = (const float*)d_in[9];
  const float* g3  = (const float*)d_in[10];
  const float* b3  = (const float*)d_in[11];

  float* out0     = (float*)d_out;
  float* out_cent = out0 + (size_t)NB*MC*CH3;
  float* out_bsel = out_cent + (size_t)NB*MC*3;

  char* base = (char*)d_ws;
  size_t off = 0;
  auto carve = [&](size_t bytes) -> char* {
    char* p = base + off;
    off = (off + bytes + 255) & ~(size_t)255;
    return p;
  };
  float* centf = (float*)carve(sizeof(float)*NB*MC*3);
  int*   cntpc = (int*)  carve(sizeof(int)*NB*MC);
  char*  zeroblk = carve(256 + 3*NSLOT*256*sizeof(float));
  int*   cnt_total = (int*)zeroblk;
  int*   taskctr   = cnt_total + 1;
  int*   progress  = cnt_total + 2;    // 8 ints
  float* Sp1 = (float*)(zeroblk + 256);
  float* Sp2 = Sp1 + NSLOT*256;
  float* Sp3 = Sp2 + NSLOT*256;
  float* SC = (float*)carve(512*sizeof(float));  // A1 B1 A2 B2 A3(128) B3(128)
  u16* y1g = (u16*)carve((size_t)NE*CH1*2);
  u16* y2g = (u16*)carve((size_t)NE*CH2*2);
  float* mxmn = (float*)carve((size_t)NB*MC*256*sizeof(float));  // 8 MB: max(128) min(128) per bm

  hipMemsetAsync(zeroblk, 0, 256 + 3*NSLOT*256*sizeof(float), stream);
  k_front<<<NBLK, 512, 0, stream>>>(x, pos, centf, out_cent, out_bsel,
                                    W1, Sp1, y1g, cntpc, cnt_total, progress, taskctr);
  k_finalize<<<1, 128, 0, stream>>>(Sp1, g1, b1, cnt_total, SC + 0,   SC + 64,  CH1);
  dim3 sg(NB*MC), sb(256);
  k_s2<<<sg, sb, 0, stream>>>(y1g, SC, W2, cntpc, Sp2, y2g);
  k_finalize<<<1, 128, 0, stream>>>(Sp2, g2, b2, cnt_total, SC + 128, SC + 192, CH2);
  k_s3<<<sg, sb, 0, stream>>>(y2g, SC, W3, cntpc, Sp3, mxmn);
  k_finalize<<<1, 128, 0, stream>>>(Sp3, g3, b3, cnt_total, SC + 256, SC + 384, CH3);
  k_s4<<<sg, 128, 0, stream>>>(mxmn, SC, out0);
}

// Round 6
// 1077.428 us; speedup vs baseline: 1.0644x; 1.0644x over previous
//
#include <hip/hip_runtime.h>
#include <stdint.h>

#define NB   8
#define NPTS 4096
#define CINV 64
#define MC   1024
#define KNB  64
#define NE   (NB*MC*KNB)
#define K1   67
#define CH1  64
#define CH2  64
#define CH3  128
#define NSLOT 64
#define CAP  2048
#define NTASK (NB*MC)
#define NBLK 256      // == #CUs

typedef unsigned short u16;
typedef unsigned int   u32;
typedef unsigned long long u64;

static __device__ __forceinline__ float bf2f(u16 b){ return __uint_as_float(((u32)b)<<16); }
static __device__ __forceinline__ u16  f2bf(float f){
  u32 u = __float_as_uint(f);
  return (u16)((u + 0x7fffu + ((u>>16)&1u)) >> 16);
}
// Exact replica of reference distance: square each diff, sum as (x+y)+z, NO fma contraction.
static __device__ __forceinline__ float d2ref(float ax,float ay,float az,
                                              float bx,float by,float bz){
  float dx = ax-bx, dy = ay-by, dz = az-bz;
  return __fadd_rn(__fadd_rn(__fmul_rn(dx,dx), __fmul_rn(dy,dy)), __fmul_rn(dz,dz));
}
static __device__ __forceinline__ float wsum(float v){
  #pragma unroll
  for (int off = 32; off > 0; off >>= 1) v += __shfl_xor(v, off);
  return v;
}
// ---- DPP primitives (pure VALU, no DS pipe) ----
template<int CTRL, int RMASK>
static __device__ __forceinline__ float dppmaxstep(float v){
  int t = __builtin_amdgcn_update_dpp(__float_as_int(v), __float_as_int(v),
                                      CTRL, RMASK, 0xF, false);
  return fmaxf(v, __int_as_float(t));
}
template<int CTRL, int RMASK>
static __device__ __forceinline__ float dppminstep(float v){
  int t = __builtin_amdgcn_update_dpp(__float_as_int(v), __float_as_int(v),
                                      CTRL, RMASK, 0xF, false);
  return fminf(v, __int_as_float(t));
}
template<int CTRL, int RMASK>
static __device__ __forceinline__ float dppaddstep(float v){
  // old = 0 so row-masked lanes add 0 (exact-once summation)
  int t = __builtin_amdgcn_update_dpp(0, __float_as_int(v), CTRL, RMASK, 0xF, false);
  return v + __int_as_float(t);
}
// Full-wave reductions; result valid in LANE 63 only.
static __device__ __forceinline__ float dppsum63(float v){
  v = dppaddstep<0xB1,0xF>(v); v = dppaddstep<0x4E,0xF>(v); v = dppaddstep<0x141,0xF>(v);
  v = dppaddstep<0x140,0xF>(v); v = dppaddstep<0x142,0xA>(v); v = dppaddstep<0x143,0xC>(v);
  return v;
}
static __device__ __forceinline__ float dppmax63(float v){
  v = dppmaxstep<0xB1,0xF>(v); v = dppmaxstep<0x4E,0xF>(v); v = dppmaxstep<0x141,0xF>(v);
  v = dppmaxstep<0x140,0xF>(v); v = dppmaxstep<0x142,0xA>(v); v = dppmaxstep<0x143,0xC>(v);
  return v;
}
static __device__ __forceinline__ float dppmin63(float v){
  v = dppminstep<0xB1,0xF>(v); v = dppminstep<0x4E,0xF>(v); v = dppminstep<0x141,0xF>(v);
  v = dppminstep<0x140,0xF>(v); v = dppminstep<0x142,0xA>(v); v = dppminstep<0x143,0xC>(v);
  return v;
}
// ---- f64-keyed argmax: key = bits[dist(f32) : ~idx]. Both positive doubles,
// so IEEE f64 ordering == u64 bit ordering: v_max_f64 == (max dist, lowest idx on tie).
static __device__ __forceinline__ double kpack(float d, int ni){
  return __hiloint2double(__float_as_int(d), ni);
}
template<int CTRL, int RMASK>
static __device__ __forceinline__ double dppk64(double k){
  int hi = __double2hiint(k), lo = __double2loint(k);
  int thi = __builtin_amdgcn_update_dpp(hi, hi, CTRL, RMASK, 0xF, false);
  int tlo = __builtin_amdgcn_update_dpp(lo, lo, CTRL, RMASK, 0xF, false);
  return fmax(k, __hiloint2double(thi, tlo));
}

// ---------------------------------------------------------------- fused front kernel
struct FpsL {
  float px[NPTS], py[NPTS], pz[NPTS];
  int   sIdx[MC];
  double candD[8];   // keyed candidates, double-buffered 2x4
  float4 cbuf[16];   // centroid staging: flush 16 rows per tile to global
};
struct WkL {
  u64   keys[CAP];        // ball-query sort keys
  float Hs[64*69];        // stage-1 H tile (odd pitch)
  int   nbrS[64];
  float red[8][16];
  float cxyz[3];
  int   scnt;
  int   task;
};
union FrontL { FpsL f; WkL w; };

__global__ __launch_bounds__(512) void k_front(const float* __restrict__ x,
                                               const float* __restrict__ pos,
                                               float* __restrict__ centf,
                                               float* __restrict__ out_cent,
                                               float* __restrict__ out_bsel,
                                               const float* __restrict__ W1,
                                               float* __restrict__ Spart,
                                               u16* __restrict__ y1g,
                                               int* __restrict__ cntpc,
                                               int* __restrict__ cnt_total,
                                               int* __restrict__ progress,
                                               int* __restrict__ taskctr) {
  __shared__ FrontL L;
  const int tid = threadIdx.x;

  if (blockIdx.x < NB) {
    // ============ FPS producer: stage with 8 waves, then waves 4-7 EXIT.
    // Remaining 4 waves (one per SIMD: no issue sharing, no sibling skew,
    // cheaper barrier) scan 16 pts/lane scalar; f64-keyed argmax.
    const int b = blockIdx.x;
    for (int i = tid; i < NPTS; i += 512) {
      size_t o = ((size_t)b*NPTS + i)*3;
      L.f.px[i] = pos[o]; L.f.py[i] = pos[o+1]; L.f.pz[i] = pos[o+2];
    }
    __syncthreads();          // 8-wave barrier (staging)
    if (tid >= 256) return;   // narrow the workgroup: barriers below sync 4 waves

    float cxr[16], cyr[16], czr[16], dist[16];
    int nio[16];
    #pragma unroll
    for (int j = 0; j < 16; ++j) {
      int p = tid*16 + j;
      cxr[j] = L.f.px[p]; cyr[j] = L.f.py[p]; czr[j] = L.f.pz[p];
      dist[j] = 1e10f;
      nio[j] = ~p;
    }
    const int lane = tid & 63, w = tid >> 6;   // w in 0..3
    float qx = L.f.px[0], qy = L.f.py[0], qz = L.f.pz[0];
    if (tid == 0) {
      L.f.sIdx[0] = 0;
      L.f.cbuf[0] = make_float4(qx, qy, qz, 0.f);
    }

    for (int it = 1; it < MC; ++it) {
      // ---- scan: pure min, no compares, no vcc
      #pragma unroll
      for (int j = 0; j < 16; ++j) {
        float d = d2ref(cxr[j], cyr[j], czr[j], qx, qy, qz);
        dist[j] = fminf(dist[j], d);
      }
      // ---- keyed pairwise tree over 16 points (15 x v_max_f64)
      double t0 = fmax(kpack(dist[0],  nio[0]),  kpack(dist[1],  nio[1]));
      double t1 = fmax(kpack(dist[2],  nio[2]),  kpack(dist[3],  nio[3]));
      double t2 = fmax(kpack(dist[4],  nio[4]),  kpack(dist[5],  nio[5]));
      double t3 = fmax(kpack(dist[6],  nio[6]),  kpack(dist[7],  nio[7]));
      double t4 = fmax(kpack(dist[8],  nio[8]),  kpack(dist[9],  nio[9]));
      double t5 = fmax(kpack(dist[10], nio[10]), kpack(dist[11], nio[11]));
      double t6 = fmax(kpack(dist[12], nio[12]), kpack(dist[13], nio[13]));
      double t7 = fmax(kpack(dist[14], nio[14]), kpack(dist[15], nio[15]));
      double u0 = fmax(t0, t1), u1 = fmax(t2, t3), u2 = fmax(t4, t5), u3 = fmax(t6, t7);
      double bk = fmax(fmax(u0, u1), fmax(u2, u3));
      // ---- wave keyed reduce (6 DPP steps), winner key valid in lane 63
      bk = dppk64<0xB1,0xF>(bk);
      bk = dppk64<0x4E,0xF>(bk);
      bk = dppk64<0x141,0xF>(bk);
      bk = dppk64<0x140,0xF>(bk);
      bk = dppk64<0x142,0xA>(bk);
      bk = dppk64<0x143,0xC>(bk);
      if (lane == 63) L.f.candD[(it & 1)*4 + w] = bk;
      __syncthreads();   // 4-wave barrier
      // ---- resolve 4 candidates branch-free (2 keyed DPP steps, all lanes uniform)
      double ck = L.f.candD[(it & 1)*4 + (lane & 3)];
      ck = dppk64<0xB1,0xF>(ck);
      ck = dppk64<0x4E,0xF>(ck);
      int wi = (int)(~(u32)__double2loint(ck));   // winning point index (uniform)
      qx = L.f.px[wi]; qy = L.f.py[wi]; qz = L.f.pz[wi];   // broadcast LDS reads
      // flush PREVIOUS 16-row tile then release-publish progress
      if ((it & 15) == 0 && tid < 16) {
        int mrow = it - 16 + tid;
        float4 cc = L.f.cbuf[tid];
        int r = b*MC + mrow;
        centf[r*3+0] = cc.x; centf[r*3+1] = cc.y; centf[r*3+2] = cc.z;
        if (tid == 0)
          __hip_atomic_store(progress + b, it, __ATOMIC_RELEASE, __HIP_MEMORY_SCOPE_AGENT);
      }
      if (tid == 0) {
        L.f.sIdx[it] = wi;
        L.f.cbuf[it & 15] = make_float4(qx, qy, qz, 0.f);
      }
    }
    __syncthreads();   // 4-wave barrier
    // final tile flush (rows MC-16..MC-1) + progress = MC
    if (tid < 16) {
      int mrow = MC - 16 + tid;
      float4 cc = L.f.cbuf[tid];
      int r = b*MC + mrow;
      centf[r*3+0] = cc.x; centf[r*3+1] = cc.y; centf[r*3+2] = cc.z;
      if (tid == 0)
        __hip_atomic_store(progress + b, MC, __ATOMIC_RELEASE, __HIP_MEMORY_SCOPE_AGENT);
    }
    // epilogue: out_cent / out_bsel from sIdx (off the critical path; 256 threads)
    for (int m2_ = tid; m2_ < MC; m2_ += 256) {
      int i = L.f.sIdx[m2_];
      int r = b*MC + m2_;
      out_cent[r*3+0] = L.f.px[i]; out_cent[r*3+1] = L.f.py[i]; out_cent[r*3+2] = L.f.pz[i];
      out_bsel[r] = (float)b;
    }
    return;
  }

  // ============ persistent workers: ball query + stage-1 per centroid (512 thr)
  for (;;) {
    if (tid == 0) {
      int t = atomicAdd(taskctr, 1);
      L.w.task = t;
      if (t < NTASK) {
        int m = t >> 3, b = t & 7;
        while (__hip_atomic_load(progress + b, __ATOMIC_ACQUIRE, __HIP_MEMORY_SCOPE_AGENT) < m + 1)
          __builtin_amdgcn_s_sleep(8);
        int bm = b*MC + m;
        L.w.cxyz[0] = __hip_atomic_load(centf + bm*3 + 0, __ATOMIC_RELAXED, __HIP_MEMORY_SCOPE_AGENT);
        L.w.cxyz[1] = __hip_atomic_load(centf + bm*3 + 1, __ATOMIC_RELAXED, __HIP_MEMORY_SCOPE_AGENT);
        L.w.cxyz[2] = __hip_atomic_load(centf + bm*3 + 2, __ATOMIC_RELAXED, __HIP_MEMORY_SCOPE_AGENT);
      }
      L.w.scnt = 0;
    }
    __syncthreads();
    const int t = L.w.task;
    if (t >= NTASK) return;
    const int m = t >> 3, b = t & 7, bm = b*MC + m;
    const float cx = L.w.cxyz[0], cy = L.w.cxyz[1], cz = L.w.cxyz[2];

    // ---- ball query (exact ref semantics)
    for (int i = tid; i < NPTS; i += 512) {
      size_t o = ((size_t)b*NPTS + i)*3;
      float d = d2ref(cx, cy, cz, pos[o], pos[o+1], pos[o+2]);
      if (d <= 0.04f) {
        int p = atomicAdd(&L.w.scnt, 1);
        if (p < CAP) L.w.keys[p] = ((u64)__float_as_uint(d) << 32) | (u32)i;
      }
    }
    __syncthreads();
    int n = L.w.scnt; if (n > CAP) n = CAP;
    int P = 64; while (P < n) P <<= 1;
    for (int i = n + tid; i < P; i += 512) L.w.keys[i] = ~0ull;
    __syncthreads();
    for (int ks = 2; ks <= P; ks <<= 1)
      for (int js = ks >> 1; js > 0; js >>= 1) {
        for (int i = tid; i < P; i += 512) {
          int l = i ^ js;
          if (l > i) {
            u64 a = L.w.keys[i], c = L.w.keys[l];
            bool up = ((i & ks) == 0);
            if ((a > c) == up) { L.w.keys[i] = c; L.w.keys[l] = a; }
          }
        }
        __syncthreads();
      }
    const int c = n < KNB ? n : KNB;
    if (tid < KNB) L.w.nbrS[tid] = (tid < c) ? (int)(u32)(L.w.keys[tid] & 0xffffffffu) : 0;
    if (tid == 0) { cntpc[bm] = c; atomicAdd(cnt_total, c); }
    __syncthreads();

    // ---- stage-1: H = [x_j, p_j - c_i] (64x67) staged in LDS
    {
      const int ge = tid >> 3, qb = tid & 7;
      const float4* xr = (const float4*)(x + ((size_t)(b*NPTS + L.w.nbrS[ge]))*CINV);
      #pragma unroll
      for (int rep = 0; rep < 2; ++rep) {
        int q = qb + rep*8;
        float4 v = xr[q];
        float* d = L.w.Hs + ge*69 + q*4;
        d[0] = v.x; d[1] = v.y; d[2] = v.z; d[3] = v.w;
      }
    }
    if (tid < 64) {
      int row = b*NPTS + L.w.nbrS[tid];
      L.w.Hs[tid*69+64] = pos[(size_t)row*3+0] - cx;
      L.w.Hs[tid*69+65] = pos[(size_t)row*3+1] - cy;
      L.w.Hs[tid*69+66] = pos[(size_t)row*3+2] - cz;
    }
    __syncthreads();

    // ---- GEMM: thread = (edge, col of 8 ch); W via wave-uniform SCALAR loads
    const int edge = tid & 63;
    const int col  = __builtin_amdgcn_readfirstlane(tid >> 6);  // 0..7
    float acc[8];
    #pragma unroll
    for (int j = 0; j < 8; ++j) acc[j] = 0.f;
    const float* hrow = L.w.Hs + edge*69;
    const float* wcol = W1 + col*8;
    for (int k = 0; k < K1; ++k) {
      float hk = hrow[k];
      const float4* w4 = (const float4*)(wcol + k*CH1);
      float4 a = w4[0], bq = w4[1];
      acc[0] = fmaf(hk, a.x,  acc[0]); acc[1] = fmaf(hk, a.y,  acc[1]);
      acc[2] = fmaf(hk, a.z,  acc[2]); acc[3] = fmaf(hk, a.w,  acc[3]);
      acc[4] = fmaf(hk, bq.x, acc[4]); acc[5] = fmaf(hk, bq.y, acc[5]);
      acc[6] = fmaf(hk, bq.z, acc[6]); acc[7] = fmaf(hk, bq.w, acc[7]);
    }
    const bool valid = edge < c;
    #pragma unroll
    for (int j = 0; j < 8; ++j) acc[j] = valid ? acc[j] : 0.f;
    u32* dst = (u32*)(y1g + ((size_t)bm*64 + edge)*CH1 + col*8);
    #pragma unroll
    for (int j = 0; j < 4; ++j)
      dst[j] = (u32)f2bf(acc[2*j]) | ((u32)f2bf(acc[2*j+1]) << 16);
    #pragma unroll
    for (int j = 0; j < 8; ++j) {
      float s = wsum(acc[j]);
      float q = wsum(acc[j]*acc[j]);
      if (edge == 0) { L.w.red[col][j] = s; L.w.red[col][8+j] = q; }
    }
    __syncthreads();
    const int slot = bm & (NSLOT-1);
    if (tid < 64)  atomicAdd(&Spart[slot*256 + tid], L.w.red[tid>>3][tid&7]);
    else if (tid < 128) {
      int cc = tid - 64;
      atomicAdd(&Spart[slot*256 + 128 + cc], L.w.red[cc>>3][8 + (cc&7)]);
    }
    // top-of-loop __syncthreads() isolates this task's LDS reads from next task's writes
  }
}

// ---------------------------------------------------------------- stage 2: relu(bn1(y1)) @ W2
__global__ __launch_bounds__(256) void k_s2(const u16* __restrict__ y1g,
                                            const float* __restrict__ SC,
                                            const float* __restrict__ W2,
                                            const int* __restrict__ cntpc,
                                            float* __restrict__ Spart,
                                            u16* __restrict__ y2g) {
  __shared__ float Hs[64*65];
  __shared__ float ABs[128];
  __shared__ float red[4][32];
  __shared__ int   cntS;
  const int tid = threadIdx.x, bm = blockIdx.x;
  if (tid == 0) cntS = cntpc[bm];
  if (tid < 128) ABs[tid] = SC[tid];            // A1(64) B1(64)
  __syncthreads();
  {
    const u32* yt = (const u32*)y1g + (size_t)bm*2048;  // 64 edges * 32 u32
    #pragma unroll
    for (int rep = 0; rep < 8; ++rep) {
      int g = rep*256 + tid;
      int e = g >> 5, c2 = g & 31, ch = c2*2;
      u32 v = yt[g];
      float lo = fmaxf(fmaf(bf2f((u16)(v & 0xffff)), ABs[ch],   ABs[64+ch]),   0.f);
      float hi = fmaxf(fmaf(bf2f((u16)(v >> 16)),    ABs[ch+1], ABs[64+ch+1]), 0.f);
      Hs[e*65 + ch] = lo; Hs[e*65 + ch + 1] = hi;
    }
  }
  __syncthreads();

  const int edge = tid & 63;
  const int col  = __builtin_amdgcn_readfirstlane(tid >> 6);
  float acc[16];
  #pragma unroll
  for (int j = 0; j < 16; ++j) acc[j] = 0.f;
  const float* hrow = Hs + edge*65;
  const float* wcol = W2 + col*16;
  for (int k = 0; k < CH1; ++k) {
    float hk = hrow[k];
    const float4* w4 = (const float4*)(wcol + k*CH2);
    #pragma unroll
    for (int q = 0; q < 4; ++q) {
      float4 wv = w4[q];
      acc[q*4+0] = fmaf(hk, wv.x, acc[q*4+0]);
      acc[q*4+1] = fmaf(hk, wv.y, acc[q*4+1]);
      acc[q*4+2] = fmaf(hk, wv.z, acc[q*4+2]);
      acc[q*4+3] = fmaf(hk, wv.w, acc[q*4+3]);
    }
  }
  const bool valid = edge < cntS;
  #pragma unroll
  for (int j = 0; j < 16; ++j) acc[j] = valid ? acc[j] : 0.f;
  u32* dst = (u32*)(y2g + ((size_t)bm*64 + edge)*CH2 + col*16);
  #pragma unroll
  for (int j = 0; j < 8; ++j)
    dst[j] = (u32)f2bf(acc[2*j]) | ((u32)f2bf(acc[2*j+1]) << 16);
  #pragma unroll
  for (int j = 0; j < 16; ++j) {
    float s = dppsum63(acc[j]);
    float q = dppsum63(acc[j]*acc[j]);
    if (edge == 63) { red[col][j] = s; red[col][16+j] = q; }
  }
  __syncthreads();
  const int slot = bm & (NSLOT-1);
  if (tid < 64)  atomicAdd(&Spart[slot*256 + tid], red[tid>>4][tid&15]);
  else if (tid < 128) {
    int c = tid - 64;
    atomicAdd(&Spart[slot*256 + 128 + c], red[c>>4][16 + (c&15)]);
  }
}

// ---------------------------------------------------------------- stage 3: relu(bn2(y2)) @ W3, + per-(bm,ch) max/min of f32 y3
__global__ __launch_bounds__(256) void k_s3(const u16* __restrict__ y2g,
                                            const float* __restrict__ SC,
                                            const float* __restrict__ W3,
                                            const int* __restrict__ cntpc,
                                            float* __restrict__ Spart,
                                            float* __restrict__ mxmn) {
  __shared__ float Hs[64*65];
  __shared__ float ABs[128];
  __shared__ float red[4][64];
  __shared__ float redm[4][64];
  __shared__ int   cntS;
  const int tid = threadIdx.x, bm = blockIdx.x;
  if (tid == 0) cntS = cntpc[bm];
  if (tid < 128) ABs[tid] = SC[128 + tid];      // A2(64) B2(64)
  __syncthreads();
  {
    const u32* yt = (const u32*)y2g + (size_t)bm*2048;
    #pragma unroll
    for (int rep = 0; rep < 8; ++rep) {
      int g = rep*256 + tid;
      int e = g >> 5, c2 = g & 31, ch = c2*2;
      u32 v = yt[g];
      float lo = fmaxf(fmaf(bf2f((u16)(v & 0xffff)), ABs[ch],   ABs[64+ch]),   0.f);
      float hi = fmaxf(fmaf(bf2f((u16)(v >> 16)),    ABs[ch+1], ABs[64+ch+1]), 0.f);
      Hs[e*65 + ch] = lo; Hs[e*65 + ch + 1] = hi;
    }
  }
  __syncthreads();

  const int edge = tid & 63;
  const int col  = __builtin_amdgcn_readfirstlane(tid >> 6);  // owns 32 of 128 ch
  float acc[32];
  #pragma unroll
  for (int j = 0; j < 32; ++j) acc[j] = 0.f;
  const float* hrow = Hs + edge*65;
  const float* wcol = W3 + col*32;
  for (int k = 0; k < CH2; ++k) {
    float hk = hrow[k];
    const float4* w4 = (const float4*)(wcol + k*CH3);
    #pragma unroll
    for (int q = 0; q < 8; ++q) {
      float4 wv = w4[q];
      acc[q*4+0] = fmaf(hk, wv.x, acc[q*4+0]);
      acc[q*4+1] = fmaf(hk, wv.y, acc[q*4+1]);
      acc[q*4+2] = fmaf(hk, wv.z, acc[q*4+2]);
      acc[q*4+3] = fmaf(hk, wv.w, acc[q*4+3]);
    }
  }
  const bool valid = edge < cntS;
  #pragma unroll
  for (int j = 0; j < 32; ++j) {
    float mxv = valid ? acc[j] : -1e30f;
    float mnv = valid ? acc[j] :  1e30f;
    float av  = valid ? acc[j] : 0.f;
    float s  = dppsum63(av);
    float q  = dppsum63(av*av);
    float mx = dppmax63(mxv);
    float mn = dppmin63(mnv);
    if (edge == 63) { red[col][j] = s; red[col][32+j] = q;
                      redm[col][j] = mx; redm[col][32+j] = mn; }
  }
  __syncthreads();
  const int slot = bm & (NSLOT-1);
  if (tid < 128) {
    atomicAdd(&Spart[slot*256 + tid], red[tid>>5][tid&31]);
    mxmn[(size_t)bm*256 + tid] = redm[tid>>5][tid&31];            // max(y3) per ch
  } else {
    int c = tid - 128;
    atomicAdd(&Spart[slot*256 + 128 + c], red[c>>5][32 + (c&31)]);
    mxmn[(size_t)bm*256 + 128 + c] = redm[c>>5][32 + (c&31)];     // min(y3) per ch
  }
}

// ---------------------------------------------------------------- stage 4: bn3+relu+maxpool from per-block max/min
// max_e relu(a*y+b) = relu(a*max_e(y)+b) for a>0 (monotone correctly-rounded ops
// commute with max); use min_e(y) for a<0. Exact vs the elementwise scan.
__global__ __launch_bounds__(128) void k_s4(const float* __restrict__ mxmn,
                                            const float* __restrict__ SC,
                                            float* __restrict__ out0) {
  const int tid = threadIdx.x, bm = blockIdx.x;
  const float a = SC[256 + tid], b = SC[384 + tid];
  const float mx = mxmn[(size_t)bm*256 + tid];
  const float mn = mxmn[(size_t)bm*256 + 128 + tid];
  const float v = (a > 0.f) ? mx : mn;
  out0[(size_t)bm*CH3 + tid] = fmaxf(fmaf(v, a, b), 0.f);
}

// ---------------------------------------------------------------- finalize
__global__ void k_finalize(const float* __restrict__ Spart,
                           const float* __restrict__ g, const float* __restrict__ bb,
                           const int* __restrict__ cnt_total,
                           float* __restrict__ Aout, float* __restrict__ Bout, int C) {
  int c = threadIdx.x;
  if (c < C) {
    float s = 0.f, q = 0.f;
    for (int sl = 0; sl < NSLOT; ++sl) {
      s += Spart[sl*256 + c];
      q += Spart[sl*256 + 128 + c];
    }
    float n = (float)(*cnt_total); if (n < 1.f) n = 1.f;
    float mu  = s / n;
    float var = q / n - mu*mu; if (var < 0.f) var = 0.f;
    float inv = 1.0f / sqrtf(var + 1e-5f);
    float a = g[c] * inv;
    Aout[c] = a;
    Bout[c] = bb[c] - mu*a;
  }
}

// ---------------------------------------------------------------- host
extern "C" void kernel_launch(void* const* d_in, const int* in_sizes, int n_in,
                              void* d_out, int out_size, void* d_ws, size_t ws_size,
                              hipStream_t stream) {
  (void)in_sizes; (void)n_in; (void)out_size; (void)ws_size;
  const float* x   = (const float*)d_in[0];
  const float* pos = (const float*)d_in[1];
  const float* W1  = (const float*)d_in[3];
  const float* g1  = (const float*)d_in[4];
  const float* b1  = (const float*)d_in[5];
  const float* W2  = (const float*)d_in[6];
  const float* g2  = (const float*)d_in[7];
  const float* b2  = (const float*)d_in[8];
  const float* W3  = (const float*)d_in[9];
  const float* g3  = (const float*)d_in[10];
  const float* b3  = (const float*)d_in[11];

  float* out0     = (float*)d_out;
  float* out_cent = out0 + (size_t)NB*MC*CH3;
  float* out_bsel = out_cent + (size_t)NB*MC*3;

  char* base = (char*)d_ws;
  size_t off = 0;
  auto carve = [&](size_t bytes) -> char* {
    char* p = base + off;
    off = (off + bytes + 255) & ~(size_t)255;
    return p;
  };
  float* centf = (float*)carve(sizeof(float)*NB*MC*3);
  int*   cntpc = (int*)  carve(sizeof(int)*NB*MC);
  char*  zeroblk = carve(256 + 3*NSLOT*256*sizeof(float));
  int*   cnt_total = (int*)zeroblk;
  int*   taskctr   = cnt_total + 1;
  int*   progress  = cnt_total + 2;    // 8 ints
  float* Sp1 = (float*)(zeroblk + 256);
  float* Sp2 = Sp1 + NSLOT*256;
  float* Sp3 = Sp2 + NSLOT*256;
  float* SC = (float*)carve(512*sizeof(float));  // A1 B1 A2 B2 A3(128) B3(128)
  u16* y1g = (u16*)carve((size_t)NE*CH1*2);
  u16* y2g = (u16*)carve((size_t)NE*CH2*2);
  float* mxmn = (float*)carve((size_t)NB*MC*256*sizeof(float));  // 8 MB: max(128) min(128) per bm

  hipMemsetAsync(zeroblk, 0, 256 + 3*NSLOT*256*sizeof(float), stream);
  k_front<<<NBLK, 512, 0, stream>>>(x, pos, centf, out_cent, out_bsel,
                                    W1, Sp1, y1g, cntpc, cnt_total, progress, taskctr);
  k_finalize<<<1, 128, 0, stream>>>(Sp1, g1, b1, cnt_total, SC + 0,   SC + 64,  CH1);
  dim3 sg(NB*MC), sb(256);
  k_s2<<<sg, sb, 0, stream>>>(y1g, SC, W2, cntpc, Sp2, y2g);
  k_finalize<<<1, 128, 0, stream>>>(Sp2, g2, b2, cnt_total, SC + 128, SC + 192, CH2);
  k_s3<<<sg, sb, 0, stream>>>(y2g, SC, W3, cntpc, Sp3, mxmn);
  k_finalize<<<1, 128, 0, stream>>>(Sp3, g3, b3, cnt_total, SC + 256, SC + 384, CH3);
  k_s4<<<sg, 128, 0, stream>>>(mxmn, SC, out0);
}

// Round 7
// 1034.790 us; speedup vs baseline: 1.1082x; 1.0412x over previous
//
#include <hip/hip_runtime.h>
#include <stdint.h>

#define NB   8
#define NPTS 4096
#define CINV 64
#define MC   1024
#define KNB  64
#define NE   (NB*MC*KNB)
#define K1   67
#define CH1  64
#define CH2  64
#define CH3  128
#define NSLOT 64
#define CAP  2048
#define NTASK (NB*MC)
#define NBLK 256      // == #CUs

typedef unsigned short u16;
typedef unsigned int   u32;
typedef unsigned long long u64;

static __device__ __forceinline__ float bf2f(u16 b){ return __uint_as_float(((u32)b)<<16); }
static __device__ __forceinline__ u16  f2bf(float f){
  u32 u = __float_as_uint(f);
  return (u16)((u + 0x7fffu + ((u>>16)&1u)) >> 16);
}
// Exact replica of reference distance: square each diff, sum as (x+y)+z, NO fma contraction.
static __device__ __forceinline__ float d2ref(float ax,float ay,float az,
                                              float bx,float by,float bz){
  float dx = ax-bx, dy = ay-by, dz = az-bz;
  return __fadd_rn(__fadd_rn(__fmul_rn(dx,dx), __fmul_rn(dy,dy)), __fmul_rn(dz,dz));
}
// ---- DPP primitives (pure VALU, no DS pipe) ----
template<int CTRL, int RMASK>
static __device__ __forceinline__ float dppmaxstep(float v){
  int t = __builtin_amdgcn_update_dpp(__float_as_int(v), __float_as_int(v),
                                      CTRL, RMASK, 0xF, false);
  return fmaxf(v, __int_as_float(t));
}
template<int CTRL, int RMASK>
static __device__ __forceinline__ float dppminstep(float v){
  int t = __builtin_amdgcn_update_dpp(__float_as_int(v), __float_as_int(v),
                                      CTRL, RMASK, 0xF, false);
  return fminf(v, __int_as_float(t));
}
template<int CTRL, int RMASK>
static __device__ __forceinline__ float dppaddstep(float v){
  // old = 0 so lanes with masked/invalid source add 0 (exact-once summation)
  int t = __builtin_amdgcn_update_dpp(0, __float_as_int(v), CTRL, RMASK, 0xF, false);
  return v + __int_as_float(t);
}
// Group-16 reductions (4 steps); EVERY lane ends with its 16-lane-group result.
static __device__ __forceinline__ float dppsum16(float v){
  v = dppaddstep<0xB1,0xF>(v); v = dppaddstep<0x4E,0xF>(v);
  v = dppaddstep<0x141,0xF>(v); v = dppaddstep<0x140,0xF>(v);
  return v;
}
static __device__ __forceinline__ float dppmax16(float v){
  v = dppmaxstep<0xB1,0xF>(v); v = dppmaxstep<0x4E,0xF>(v);
  v = dppmaxstep<0x141,0xF>(v); v = dppmaxstep<0x140,0xF>(v);
  return v;
}
static __device__ __forceinline__ float dppmin16(float v){
  v = dppminstep<0xB1,0xF>(v); v = dppminstep<0x4E,0xF>(v);
  v = dppminstep<0x141,0xF>(v); v = dppminstep<0x140,0xF>(v);
  return v;
}
// ---- f64-keyed argmax: key = bits[dist(f32) : ~idx]. Both positive doubles,
// so IEEE f64 ordering == u64 bit ordering: v_max_f64 == (max dist, lowest idx on tie).
static __device__ __forceinline__ double kpack(float d, int ni){
  return __hiloint2double(__float_as_int(d), ni);
}
template<int CTRL, int RMASK>
static __device__ __forceinline__ double dppk64(double k){
  int hi = __double2hiint(k), lo = __double2loint(k);
  int thi = __builtin_amdgcn_update_dpp(hi, hi, CTRL, RMASK, 0xF, false);
  int tlo = __builtin_amdgcn_update_dpp(lo, lo, CTRL, RMASK, 0xF, false);
  return fmax(k, __hiloint2double(thi, tlo));
}

// ---------------------------------------------------------------- fused front kernel
struct FpsL {
  float px[NPTS], py[NPTS], pz[NPTS];
  int   sIdx[MC];
  double candD[8];   // keyed candidates, double-buffered 2x4 (32B-contig per phase)
  float4 cbuf[16];   // centroid staging: flush 16 rows per tile to global
};
struct WkL {
  u64   keys[CAP];        // ball-query sort keys
  float Hs[64*69];        // stage-1 H tile (odd pitch)
  int   nbrS[64];
  float red[8][16][4];    // [col][s(8)+q(8)][group16]
  float cxyz[3];
  int   scnt;
  int   task;
};
union FrontL { FpsL f; WkL w; };

__global__ __launch_bounds__(512) void k_front(const float* __restrict__ x,
                                               const float* __restrict__ pos,
                                               float* __restrict__ centf,
                                               float* __restrict__ out_cent,
                                               float* __restrict__ out_bsel,
                                               const float* __restrict__ W1,
                                               float* __restrict__ Spart,
                                               u16* __restrict__ y1g,
                                               int* __restrict__ cntpc,
                                               int* __restrict__ cnt_total,
                                               int* __restrict__ progress,
                                               int* __restrict__ taskctr) {
  __shared__ FrontL L;
  const int tid = threadIdx.x;

  if (blockIdx.x < NB) {
    // ============ FPS producer: stage with 8 waves, then waves 4-7 EXIT.
    // 4 waves (one per SIMD), 16 pts/lane scalar scan, f64-keyed argmax.
    const int b = blockIdx.x;
    for (int i = tid; i < NPTS; i += 512) {
      size_t o = ((size_t)b*NPTS + i)*3;
      L.f.px[i] = pos[o]; L.f.py[i] = pos[o+1]; L.f.pz[i] = pos[o+2];
    }
    __syncthreads();          // 8-wave barrier (staging)
    if (tid >= 256) return;   // narrow the workgroup: barriers below sync 4 waves

    float cxr[16], cyr[16], czr[16], dist[16];
    int nio[16];
    #pragma unroll
    for (int j = 0; j < 16; ++j) {
      int p = tid*16 + j;
      cxr[j] = L.f.px[p]; cyr[j] = L.f.py[p]; czr[j] = L.f.pz[p];
      dist[j] = 1e10f;
      nio[j] = ~p;
    }
    const int lane = tid & 63, w = tid >> 6;   // w in 0..3
    float qx = L.f.px[0], qy = L.f.py[0], qz = L.f.pz[0];
    if (tid == 0) {
      L.f.sIdx[0] = 0;
      L.f.cbuf[0] = make_float4(qx, qy, qz, 0.f);
    }

    for (int it = 1; it < MC; ++it) {
      // ---- scan: pure min, no compares, no vcc
      #pragma unroll
      for (int j = 0; j < 16; ++j) {
        float d = d2ref(cxr[j], cyr[j], czr[j], qx, qy, qz);
        dist[j] = fminf(dist[j], d);
      }
      // ---- keyed pairwise tree over 16 points (15 x v_max_f64)
      double t0 = fmax(kpack(dist[0],  nio[0]),  kpack(dist[1],  nio[1]));
      double t1 = fmax(kpack(dist[2],  nio[2]),  kpack(dist[3],  nio[3]));
      double t2 = fmax(kpack(dist[4],  nio[4]),  kpack(dist[5],  nio[5]));
      double t3 = fmax(kpack(dist[6],  nio[6]),  kpack(dist[7],  nio[7]));
      double t4 = fmax(kpack(dist[8],  nio[8]),  kpack(dist[9],  nio[9]));
      double t5 = fmax(kpack(dist[10], nio[10]), kpack(dist[11], nio[11]));
      double t6 = fmax(kpack(dist[12], nio[12]), kpack(dist[13], nio[13]));
      double t7 = fmax(kpack(dist[14], nio[14]), kpack(dist[15], nio[15]));
      double u0 = fmax(t0, t1), u1 = fmax(t2, t3), u2 = fmax(t4, t5), u3 = fmax(t6, t7);
      double bk = fmax(fmax(u0, u1), fmax(u2, u3));
      // ---- wave keyed reduce (6 DPP steps), winner key valid in lane 63
      bk = dppk64<0xB1,0xF>(bk);
      bk = dppk64<0x4E,0xF>(bk);
      bk = dppk64<0x141,0xF>(bk);
      bk = dppk64<0x140,0xF>(bk);
      bk = dppk64<0x142,0xA>(bk);
      bk = dppk64<0x143,0xC>(bk);
      if (lane == 63) L.f.candD[(it & 1)*4 + w] = bk;
      __syncthreads();   // 4-wave barrier
      // ---- resolve: every lane reads all 4 candidates (2x ds_read_b128,
      // broadcast, one latency) + 3 in-lane v_max_f64. No DPP on the chain.
      const double* cd = &L.f.candD[(it & 1)*4];
      double c0 = cd[0], c1 = cd[1], c2 = cd[2], c3 = cd[3];
      double ck = fmax(fmax(c0, c1), fmax(c2, c3));
      int wi = (int)(~(u32)__double2loint(ck));   // winning point index (uniform)
      qx = L.f.px[wi]; qy = L.f.py[wi]; qz = L.f.pz[wi];   // broadcast LDS reads
      // flush PREVIOUS 16-row tile then release-publish progress
      if ((it & 15) == 0 && tid < 16) {
        int mrow = it - 16 + tid;
        float4 cc = L.f.cbuf[tid];
        int r = b*MC + mrow;
        centf[r*3+0] = cc.x; centf[r*3+1] = cc.y; centf[r*3+2] = cc.z;
        if (tid == 0)
          __hip_atomic_store(progress + b, it, __ATOMIC_RELEASE, __HIP_MEMORY_SCOPE_AGENT);
      }
      if (tid == 0) {
        L.f.sIdx[it] = wi;
        L.f.cbuf[it & 15] = make_float4(qx, qy, qz, 0.f);
      }
    }
    __syncthreads();   // 4-wave barrier
    // final tile flush (rows MC-16..MC-1) + progress = MC
    if (tid < 16) {
      int mrow = MC - 16 + tid;
      float4 cc = L.f.cbuf[tid];
      int r = b*MC + mrow;
      centf[r*3+0] = cc.x; centf[r*3+1] = cc.y; centf[r*3+2] = cc.z;
      if (tid == 0)
        __hip_atomic_store(progress + b, MC, __ATOMIC_RELEASE, __HIP_MEMORY_SCOPE_AGENT);
    }
    // epilogue: out_cent / out_bsel from sIdx (off the critical path; 256 threads)
    for (int m2_ = tid; m2_ < MC; m2_ += 256) {
      int i = L.f.sIdx[m2_];
      int r = b*MC + m2_;
      out_cent[r*3+0] = L.f.px[i]; out_cent[r*3+1] = L.f.py[i]; out_cent[r*3+2] = L.f.pz[i];
      out_bsel[r] = (float)b;
    }
    return;
  }

  // ============ persistent workers: ball query + stage-1 per centroid (512 thr)
  for (;;) {
    if (tid == 0) {
      int t = atomicAdd(taskctr, 1);
      L.w.task = t;
      if (t < NTASK) {
        int m = t >> 3, b = t & 7;
        while (__hip_atomic_load(progress + b, __ATOMIC_ACQUIRE, __HIP_MEMORY_SCOPE_AGENT) < m + 1)
          __builtin_amdgcn_s_sleep(8);
        int bm = b*MC + m;
        L.w.cxyz[0] = __hip_atomic_load(centf + bm*3 + 0, __ATOMIC_RELAXED, __HIP_MEMORY_SCOPE_AGENT);
        L.w.cxyz[1] = __hip_atomic_load(centf + bm*3 + 1, __ATOMIC_RELAXED, __HIP_MEMORY_SCOPE_AGENT);
        L.w.cxyz[2] = __hip_atomic_load(centf + bm*3 + 2, __ATOMIC_RELAXED, __HIP_MEMORY_SCOPE_AGENT);
      }
      L.w.scnt = 0;
    }
    __syncthreads();
    const int t = L.w.task;
    if (t >= NTASK) return;
    const int m = t >> 3, b = t & 7, bm = b*MC + m;
    const float cx = L.w.cxyz[0], cy = L.w.cxyz[1], cz = L.w.cxyz[2];

    // ---- ball query (exact ref semantics)
    for (int i = tid; i < NPTS; i += 512) {
      size_t o = ((size_t)b*NPTS + i)*3;
      float d = d2ref(cx, cy, cz, pos[o], pos[o+1], pos[o+2]);
      if (d <= 0.04f) {
        int p = atomicAdd(&L.w.scnt, 1);
        if (p < CAP) L.w.keys[p] = ((u64)__float_as_uint(d) << 32) | (u32)i;
      }
    }
    __syncthreads();
    int n = L.w.scnt; if (n > CAP) n = CAP;
    int P = 64; while (P < n) P <<= 1;
    for (int i = n + tid; i < P; i += 512) L.w.keys[i] = ~0ull;
    __syncthreads();
    for (int ks = 2; ks <= P; ks <<= 1)
      for (int js = ks >> 1; js > 0; js >>= 1) {
        for (int i = tid; i < P; i += 512) {
          int l = i ^ js;
          if (l > i) {
            u64 a = L.w.keys[i], c = L.w.keys[l];
            bool up = ((i & ks) == 0);
            if ((a > c) == up) { L.w.keys[i] = c; L.w.keys[l] = a; }
          }
        }
        __syncthreads();
      }
    const int c = n < KNB ? n : KNB;
    if (tid < KNB) L.w.nbrS[tid] = (tid < c) ? (int)(u32)(L.w.keys[tid] & 0xffffffffu) : 0;
    if (tid == 0) { cntpc[bm] = c; atomicAdd(cnt_total, c); }
    __syncthreads();

    // ---- stage-1: H = [x_j, p_j - c_i] (64x67) staged in LDS
    {
      const int ge = tid >> 3, qb = tid & 7;
      const float4* xr = (const float4*)(x + ((size_t)(b*NPTS + L.w.nbrS[ge]))*CINV);
      #pragma unroll
      for (int rep = 0; rep < 2; ++rep) {
        int q = qb + rep*8;
        float4 v = xr[q];
        float* d = L.w.Hs + ge*69 + q*4;
        d[0] = v.x; d[1] = v.y; d[2] = v.z; d[3] = v.w;
      }
    }
    if (tid < 64) {
      int row = b*NPTS + L.w.nbrS[tid];
      L.w.Hs[tid*69+64] = pos[(size_t)row*3+0] - cx;
      L.w.Hs[tid*69+65] = pos[(size_t)row*3+1] - cy;
      L.w.Hs[tid*69+66] = pos[(size_t)row*3+2] - cz;
    }
    __syncthreads();

    // ---- GEMM: thread = (edge, col of 8 ch); W via wave-uniform SCALAR loads
    const int edge = tid & 63;
    const int col  = __builtin_amdgcn_readfirstlane(tid >> 6);  // 0..7
    float acc[8];
    #pragma unroll
    for (int j = 0; j < 8; ++j) acc[j] = 0.f;
    const float* hrow = L.w.Hs + edge*69;
    const float* wcol = W1 + col*8;
    for (int k = 0; k < K1; ++k) {
      float hk = hrow[k];
      const float4* w4 = (const float4*)(wcol + k*CH1);
      float4 a = w4[0], bq = w4[1];
      acc[0] = fmaf(hk, a.x,  acc[0]); acc[1] = fmaf(hk, a.y,  acc[1]);
      acc[2] = fmaf(hk, a.z,  acc[2]); acc[3] = fmaf(hk, a.w,  acc[3]);
      acc[4] = fmaf(hk, bq.x, acc[4]); acc[5] = fmaf(hk, bq.y, acc[5]);
      acc[6] = fmaf(hk, bq.z, acc[6]); acc[7] = fmaf(hk, bq.w, acc[7]);
    }
    const bool valid = edge < c;
    #pragma unroll
    for (int j = 0; j < 8; ++j) acc[j] = valid ? acc[j] : 0.f;
    u32* dst = (u32*)(y1g + ((size_t)bm*64 + edge)*CH1 + col*8);
    #pragma unroll
    for (int j = 0; j < 4; ++j)
      dst[j] = (u32)f2bf(acc[2*j]) | ((u32)f2bf(acc[2*j+1]) << 16);
    // group-16 DPP reductions (pure VALU), 4 partials per value
    #pragma unroll
    for (int j = 0; j < 8; ++j) {
      float s = dppsum16(acc[j]);
      float q = dppsum16(acc[j]*acc[j]);
      if ((edge & 15) == 0) {
        L.w.red[col][j][edge>>4]   = s;
        L.w.red[col][8+j][edge>>4] = q;
      }
    }
    __syncthreads();
    const int slot = bm & (NSLOT-1);
    if (tid < 64) {
      float4 g = *(const float4*)&L.w.red[tid>>3][tid&7][0];
      atomicAdd(&Spart[slot*256 + tid], (g.x+g.y)+(g.z+g.w));
    } else if (tid < 128) {
      int cc = tid - 64;
      float4 g = *(const float4*)&L.w.red[cc>>3][8+(cc&7)][0];
      atomicAdd(&Spart[slot*256 + 128 + cc], (g.x+g.y)+(g.z+g.w));
    }
    // top-of-loop __syncthreads() isolates this task's LDS reads from next task's writes
  }
}

// ---------------------------------------------------------------- stage 2: relu(bn1(y1)) @ W2
__global__ __launch_bounds__(256) void k_s2(const u16* __restrict__ y1g,
                                            const float* __restrict__ SC,
                                            const float* __restrict__ W2,
                                            const int* __restrict__ cntpc,
                                            float* __restrict__ Spart,
                                            u16* __restrict__ y2g) {
  __shared__ float Hs[64*65];
  __shared__ float ABs[128];
  __shared__ float red[4][32][4];
  __shared__ int   cntS;
  const int tid = threadIdx.x, bm = blockIdx.x;
  if (tid == 0) cntS = cntpc[bm];
  if (tid < 128) ABs[tid] = SC[tid];            // A1(64) B1(64)
  __syncthreads();
  {
    const u32* yt = (const u32*)y1g + (size_t)bm*2048;  // 64 edges * 32 u32
    #pragma unroll
    for (int rep = 0; rep < 8; ++rep) {
      int g = rep*256 + tid;
      int e = g >> 5, c2 = g & 31, ch = c2*2;
      u32 v = yt[g];
      float lo = fmaxf(fmaf(bf2f((u16)(v & 0xffff)), ABs[ch],   ABs[64+ch]),   0.f);
      float hi = fmaxf(fmaf(bf2f((u16)(v >> 16)),    ABs[ch+1], ABs[64+ch+1]), 0.f);
      Hs[e*65 + ch] = lo; Hs[e*65 + ch + 1] = hi;
    }
  }
  __syncthreads();

  const int edge = tid & 63;
  const int col  = __builtin_amdgcn_readfirstlane(tid >> 6);
  float acc[16];
  #pragma unroll
  for (int j = 0; j < 16; ++j) acc[j] = 0.f;
  const float* hrow = Hs + edge*65;
  const float* wcol = W2 + col*16;
  for (int k = 0; k < CH1; ++k) {
    float hk = hrow[k];
    const float4* w4 = (const float4*)(wcol + k*CH2);
    #pragma unroll
    for (int q = 0; q < 4; ++q) {
      float4 wv = w4[q];
      acc[q*4+0] = fmaf(hk, wv.x, acc[q*4+0]);
      acc[q*4+1] = fmaf(hk, wv.y, acc[q*4+1]);
      acc[q*4+2] = fmaf(hk, wv.z, acc[q*4+2]);
      acc[q*4+3] = fmaf(hk, wv.w, acc[q*4+3]);
    }
  }
  const bool valid = edge < cntS;
  #pragma unroll
  for (int j = 0; j < 16; ++j) acc[j] = valid ? acc[j] : 0.f;
  u32* dst = (u32*)(y2g + ((size_t)bm*64 + edge)*CH2 + col*16);
  #pragma unroll
  for (int j = 0; j < 8; ++j)
    dst[j] = (u32)f2bf(acc[2*j]) | ((u32)f2bf(acc[2*j+1]) << 16);
  #pragma unroll
  for (int j = 0; j < 16; ++j) {
    float s = dppsum16(acc[j]);
    float q = dppsum16(acc[j]*acc[j]);
    if ((edge & 15) == 0) {
      red[col][j][edge>>4]    = s;
      red[col][16+j][edge>>4] = q;
    }
  }
  __syncthreads();
  const int slot = bm & (NSLOT-1);
  if (tid < 64) {
    float4 g = *(const float4*)&red[tid>>4][tid&15][0];
    atomicAdd(&Spart[slot*256 + tid], (g.x+g.y)+(g.z+g.w));
  } else if (tid < 128) {
    int c = tid - 64;
    float4 g = *(const float4*)&red[c>>4][16+(c&15)][0];
    atomicAdd(&Spart[slot*256 + 128 + c], (g.x+g.y)+(g.z+g.w));
  }
}

// ---------------------------------------------------------------- stage 3: relu(bn2(y2)) @ W3, + per-(bm,ch) max/min of f32 y3
__global__ __launch_bounds__(256) void k_s3(const u16* __restrict__ y2g,
                                            const float* __restrict__ SC,
                                            const float* __restrict__ W3,
                                            const int* __restrict__ cntpc,
                                            float* __restrict__ Spart,
                                            float* __restrict__ mxmn) {
  __shared__ float Hs[64*65];
  __shared__ float ABs[128];
  __shared__ float red[4][64][4];
  __shared__ float redm[4][64][4];
  __shared__ int   cntS;
  const int tid = threadIdx.x, bm = blockIdx.x;
  if (tid == 0) cntS = cntpc[bm];
  if (tid < 128) ABs[tid] = SC[128 + tid];      // A2(64) B2(64)
  __syncthreads();
  {
    const u32* yt = (const u32*)y2g + (size_t)bm*2048;
    #pragma unroll
    for (int rep = 0; rep < 8; ++rep) {
      int g = rep*256 + tid;
      int e = g >> 5, c2 = g & 31, ch = c2*2;
      u32 v = yt[g];
      float lo = fmaxf(fmaf(bf2f((u16)(v & 0xffff)), ABs[ch],   ABs[64+ch]),   0.f);
      float hi = fmaxf(fmaf(bf2f((u16)(v >> 16)),    ABs[ch+1], ABs[64+ch+1]), 0.f);
      Hs[e*65 + ch] = lo; Hs[e*65 + ch + 1] = hi;
    }
  }
  __syncthreads();

  const int edge = tid & 63;
  const int col  = __builtin_amdgcn_readfirstlane(tid >> 6);  // owns 32 of 128 ch
  float acc[32];
  #pragma unroll
  for (int j = 0; j < 32; ++j) acc[j] = 0.f;
  const float* hrow = Hs + edge*65;
  const float* wcol = W3 + col*32;
  for (int k = 0; k < CH2; ++k) {
    float hk = hrow[k];
    const float4* w4 = (const float4*)(wcol + k*CH3);
    #pragma unroll
    for (int q = 0; q < 8; ++q) {
      float4 wv = w4[q];
      acc[q*4+0] = fmaf(hk, wv.x, acc[q*4+0]);
      acc[q*4+1] = fmaf(hk, wv.y, acc[q*4+1]);
      acc[q*4+2] = fmaf(hk, wv.z, acc[q*4+2]);
      acc[q*4+3] = fmaf(hk, wv.w, acc[q*4+3]);
    }
  }
  const bool valid = edge < cntS;
  #pragma unroll
  for (int j = 0; j < 32; ++j) {
    float mxv = valid ? acc[j] : -1e30f;
    float mnv = valid ? acc[j] :  1e30f;
    float av  = valid ? acc[j] : 0.f;
    float s  = dppsum16(av);
    float q  = dppsum16(av*av);
    float mx = dppmax16(mxv);
    float mn = dppmin16(mnv);
    if ((edge & 15) == 0) {
      red[col][j][edge>>4]     = s;
      red[col][32+j][edge>>4]  = q;
      redm[col][j][edge>>4]    = mx;
      redm[col][32+j][edge>>4] = mn;
    }
  }
  __syncthreads();
  const int slot = bm & (NSLOT-1);
  if (tid < 128) {
    float4 g = *(const float4*)&red[tid>>5][tid&31][0];
    atomicAdd(&Spart[slot*256 + tid], (g.x+g.y)+(g.z+g.w));
    float4 gm = *(const float4*)&redm[tid>>5][tid&31][0];
    mxmn[(size_t)bm*256 + tid] = fmaxf(fmaxf(gm.x, gm.y), fmaxf(gm.z, gm.w));
  } else {
    int c = tid - 128;
    float4 g = *(const float4*)&red[c>>5][32+(c&31)][0];
    atomicAdd(&Spart[slot*256 + 128 + c], (g.x+g.y)+(g.z+g.w));
    float4 gm = *(const float4*)&redm[c>>5][32+(c&31)][0];
    mxmn[(size_t)bm*256 + 128 + c] = fminf(fminf(gm.x, gm.y), fminf(gm.z, gm.w));
  }
}

// ---------------------------------------------------------------- stage 4: bn3+relu+maxpool from per-block max/min
// max_e relu(a*y+b) = relu(a*max_e(y)+b) for a>0 (monotone correctly-rounded ops
// commute with max); use min_e(y) for a<0. Exact vs the elementwise scan.
__global__ __launch_bounds__(128) void k_s4(const float* __restrict__ mxmn,
                                            const float* __restrict__ SC,
                                            float* __restrict__ out0) {
  const int tid = threadIdx.x, bm = blockIdx.x;
  const float a = SC[256 + tid], b = SC[384 + tid];
  const float mx = mxmn[(size_t)bm*256 + tid];
  const float mn = mxmn[(size_t)bm*256 + 128 + tid];
  const float v = (a > 0.f) ? mx : mn;
  out0[(size_t)bm*CH3 + tid] = fmaxf(fmaf(v, a, b), 0.f);
}

// ---------------------------------------------------------------- finalize
__global__ void k_finalize(const float* __restrict__ Spart,
                           const float* __restrict__ g, const float* __restrict__ bb,
                           const int* __restrict__ cnt_total,
                           float* __restrict__ Aout, float* __restrict__ Bout, int C) {
  int c = threadIdx.x;
  if (c < C) {
    float s = 0.f, q = 0.f;
    for (int sl = 0; sl < NSLOT; ++sl) {
      s += Spart[sl*256 + c];
      q += Spart[sl*256 + 128 + c];
    }
    float n = (float)(*cnt_total); if (n < 1.f) n = 1.f;
    float mu  = s / n;
    float var = q / n - mu*mu; if (var < 0.f) var = 0.f;
    float inv = 1.0f / sqrtf(var + 1e-5f);
    float a = g[c] * inv;
    Aout[c] = a;
    Bout[c] = bb[c] - mu*a;
  }
}

// ---------------------------------------------------------------- host
extern "C" void kernel_launch(void* const* d_in, const int* in_sizes, int n_in,
                              void* d_out, int out_size, void* d_ws, size_t ws_size,
                              hipStream_t stream) {
  (void)in_sizes; (void)n_in; (void)out_size; (void)ws_size;
  const float* x   = (const float*)d_in[0];
  const float* pos = (const float*)d_in[1];
  const float* W1  = (const float*)d_in[3];
  const float* g1  = (const float*)d_in[4];
  const float* b1  = (const float*)d_in[5];
  const float* W2  = (const float*)d_in[6];
  const float* g2  = (const float*)d_in[7];
  const float* b2  = (const float*)d_in[8];
  const float* W3  = (const float*)d_in[9];
  const float* g3  = (const float*)d_in[10];
  const float* b3  = (const float*)d_in[11];

  float* out0     = (float*)d_out;
  float* out_cent = out0 + (size_t)NB*MC*CH3;
  float* out_bsel = out_cent + (size_t)NB*MC*3;

  char* base = (char*)d_ws;
  size_t off = 0;
  auto carve = [&](size_t bytes) -> char* {
    char* p = base + off;
    off = (off + bytes + 255) & ~(size_t)255;
    return p;
  };
  float* centf = (float*)carve(sizeof(float)*NB*MC*3);
  int*   cntpc = (int*)  carve(sizeof(int)*NB*MC);
  char*  zeroblk = carve(256 + 3*NSLOT*256*sizeof(float));
  int*   cnt_total = (int*)zeroblk;
  int*   taskctr   = cnt_total + 1;
  int*   progress  = cnt_total + 2;    // 8 ints
  float* Sp1 = (float*)(zeroblk + 256);
  float* Sp2 = Sp1 + NSLOT*256;
  float* Sp3 = Sp2 + NSLOT*256;
  float* SC = (float*)carve(512*sizeof(float));  // A1 B1 A2 B2 A3(128) B3(128)
  u16* y1g = (u16*)carve((size_t)NE*CH1*2);
  u16* y2g = (u16*)carve((size_t)NE*CH2*2);
  float* mxmn = (float*)carve((size_t)NB*MC*256*sizeof(float));  // 8 MB: max(128) min(128) per bm

  hipMemsetAsync(zeroblk, 0, 256 + 3*NSLOT*256*sizeof(float), stream);
  k_front<<<NBLK, 512, 0, stream>>>(x, pos, centf, out_cent, out_bsel,
                                    W1, Sp1, y1g, cntpc, cnt_total, progress, taskctr);
  k_finalize<<<1, 128, 0, stream>>>(Sp1, g1, b1, cnt_total, SC + 0,   SC + 64,  CH1);
  dim3 sg(NB*MC), sb(256);
  k_s2<<<sg, sb, 0, stream>>>(y1g, SC, W2, cntpc, Sp2, y2g);
  k_finalize<<<1, 128, 0, stream>>>(Sp2, g2, b2, cnt_total, SC + 128, SC + 192, CH2);
  k_s3<<<sg, sb, 0, stream>>>(y2g, SC, W3, cntpc, Sp3, mxmn);
  k_finalize<<<1, 128, 0, stream>>>(Sp3, g3, b3, cnt_total, SC + 256, SC + 384, CH3);
  k_s4<<<sg, 128, 0, stream>>>(mxmn, SC, out0);
}